// Round 2
// baseline (1174.515 us; speedup 1.0000x reference)
//
#include <hip/hip_runtime.h>
#include <math.h>

static __device__ __forceinline__ float sigmoidf_fast(float x){
  return __builtin_amdgcn_rcpf(1.f + __expf(-x));
}
static __device__ __forceinline__ float softplusf_dev(float x){
  return (x > 20.f) ? x : log1pf(__expf(x));
}

// ---------------- prep kernels ----------------
__global__ void k_prep_node(const float* __restrict__ rho_raw, const float* __restrict__ lib,
                            float* __restrict__ rho, float* __restrict__ loglib, int N){
  int i = blockIdx.x*256 + threadIdx.x;
  if (i < N){
    rho[i]    = sigmoidf_fast(rho_raw[i]);
    loglib[i] = __logf(fmaxf(lib[i], 1e-8f));
  }
}

__global__ void k_prep_W(const float* __restrict__ W_raw, float* __restrict__ WT, int C, int K){
  int i = blockIdx.x*256 + threadIdx.x;
  if (i < C*K){
    int k = i / C, c = i - k*C;
    WT[i] = softplusf_dev(W_raw[c*K + k]);   // WT[k][c]
  }
}

__global__ void k_prep_bcorr(const float* __restrict__ P, const float* __restrict__ Q,
                             float* __restrict__ bcorr, int S, int R, int C){
  __shared__ float pm[64];
  int t = threadIdx.x;
  if (t < R){
    float s = 0.f;
    for (int i = 0; i < S; ++i) s += P[i*R + t];
    pm[t] = s / (float)S;
  }
  __syncthreads();
  for (int c = t; c < C; c += 256){
    for (int s8 = 0; s8 < S; ++s8){
      float a = 0.f;
      for (int r = 0; r < R; ++r) a += (P[s8*R + r] - pm[r]) * Q[c*R + r];
      bcorr[s8*C + c] = a;
    }
  }
}

// Wg[k][j<64] = gw1[k][j] (src part); Wg[k][64+j] = gw1[64+k][j] (dst part)
__global__ void k_repack(const float* __restrict__ gw1, const float* __restrict__ gb1,
                         float* __restrict__ Wg, float* __restrict__ biasg){
  int i = blockIdx.x*256 + threadIdx.x;
  if (i < 64*128){
    int k = i >> 7, j = i & 127;
    Wg[i] = (j < 64) ? gw1[k*64 + j] : gw1[(64 + k)*64 + (j - 64)];
  }
  if (i < 128) biasg[i] = (i < 64) ? 0.f : gb1[i - 64];
}

// ---------------- CSR build ----------------
__global__ void k_hist(const int* __restrict__ dst, int* __restrict__ cnt, int E){
  int i = blockIdx.x*256 + threadIdx.x;
  if (i < E) atomicAdd(&cnt[dst[i]], 1);
}

__global__ void k_scan1(const int* __restrict__ cnt, int* __restrict__ offs,
                        int* __restrict__ blksum, int N){
  __shared__ int s[1024];
  int t = threadIdx.x;
  int i = blockIdx.x*1024 + t;
  int v = (i < N) ? cnt[i] : 0;
  s[t] = v;
  __syncthreads();
  for (int off = 1; off < 1024; off <<= 1){
    int a = (t >= off) ? s[t-off] : 0;
    __syncthreads();
    s[t] += a;
    __syncthreads();
  }
  if (i < N) offs[i] = s[t] - v;
  if (t == 1023) blksum[blockIdx.x] = s[t];
}

__global__ void k_scan2(int* __restrict__ blksum, int nblk){
  if (threadIdx.x == 0 && blockIdx.x == 0){
    int run = 0;
    for (int i = 0; i < nblk; ++i){ int t = blksum[i]; blksum[i] = run; run += t; }
  }
}

__global__ void k_scan3(int* __restrict__ offs, const int* __restrict__ blksum, int N, int E){
  int i = blockIdx.x*256 + threadIdx.x;
  if (i < N) offs[i] += blksum[i >> 10];
  else if (i == N) offs[N] = E;
}

__global__ void k_fill(const int* __restrict__ src, const int* __restrict__ dst,
                       const float* __restrict__ base_w, const float* __restrict__ dist,
                       const float* __restrict__ rho,
                       const int* __restrict__ offs, int* __restrict__ fill,
                       float4* __restrict__ csr4, int E){
  int i = blockIdx.x*256 + threadIdx.x;
  if (i < E){
    int d = dst[i];
    int p = offs[d] + atomicAdd(&fill[d], 1);
    int s = src[i];
    csr4[p] = make_float4(__int_as_float(s), dist[i], base_w[i]*rho[s], __int_as_float(d));
  }
}

// ---------------- encoder layer 1: h1 = relu(X @ W1 + b1) ----------------
// 64 rows x 64 cols per block, BK=32, transposed X tile, register prefetch.
__global__ __launch_bounds__(256) void k_enc1(const float* __restrict__ X,
                                              const float* __restrict__ W1,
                                              const float* __restrict__ b1,
                                              float* __restrict__ h1, int N, int C){
  __shared__ float XsT[32*68];   // [k][row], pad 68
  __shared__ float Ws[32*64];    // [k][col]
  int tid = threadIdx.x;
  int row0 = blockIdx.x*64;
  int xr = tid >> 2, xk = (tid & 3)*8;     // X loader: row xr, k range [xk, xk+8)
  int wk = tid >> 3, wc = (tid & 7)*8;     // W loader: k wk, cols [wc, wc+8)
  int row = row0 + xr;
  bool okR = row < N;
  const float* xrow = X + (size_t)(okR ? row : 0)*C;

  float4 xa, xb, wa, wb;
  auto loadX = [&](int k0){
    int k = k0 + xk;
    xa = (okR && k + 4 <= C) ? *(const float4*)(xrow + k)     : make_float4(0,0,0,0);
    xb = (okR && k + 8 <= C) ? *(const float4*)(xrow + k + 4) : make_float4(0,0,0,0);
  };
  auto loadW = [&](int k0){
    int k = k0 + wk;
    if (k < C){
      wa = *(const float4*)(W1 + (size_t)k*64 + wc);
      wb = *(const float4*)(W1 + (size_t)k*64 + wc + 4);
    } else { wa = make_float4(0,0,0,0); wb = make_float4(0,0,0,0); }
  };

  int tx = tid & 15, ty = tid >> 4;
  float acc[4][4];
  #pragma unroll
  for (int p = 0; p < 4; ++p){ acc[p][0]=0; acc[p][1]=0; acc[p][2]=0; acc[p][3]=0; }

  loadX(0); loadW(0);
  for (int k0 = 0; k0 < C; k0 += 32){
    XsT[(xk+0)*68 + xr] = xa.x;  XsT[(xk+1)*68 + xr] = xa.y;
    XsT[(xk+2)*68 + xr] = xa.z;  XsT[(xk+3)*68 + xr] = xa.w;
    XsT[(xk+4)*68 + xr] = xb.x;  XsT[(xk+5)*68 + xr] = xb.y;
    XsT[(xk+6)*68 + xr] = xb.z;  XsT[(xk+7)*68 + xr] = xb.w;
    *(float4*)(Ws + wk*64 + wc)     = wa;
    *(float4*)(Ws + wk*64 + wc + 4) = wb;
    __syncthreads();
    if (k0 + 32 < C){ loadX(k0+32); loadW(k0+32); }
    #pragma unroll
    for (int k = 0; k < 32; ++k){
      float4 wv = *(const float4*)(Ws + k*64 + tx*4);
      float4 xv = *(const float4*)(XsT + k*68 + ty*4);
      float xp[4] = {xv.x, xv.y, xv.z, xv.w};
      #pragma unroll
      for (int p = 0; p < 4; ++p){
        acc[p][0] = fmaf(xp[p], wv.x, acc[p][0]);
        acc[p][1] = fmaf(xp[p], wv.y, acc[p][1]);
        acc[p][2] = fmaf(xp[p], wv.z, acc[p][2]);
        acc[p][3] = fmaf(xp[p], wv.w, acc[p][3]);
      }
    }
    __syncthreads();
  }
  float4 bv = *(const float4*)(b1 + tx*4);
  #pragma unroll
  for (int p = 0; p < 4; ++p){
    int r = row0 + ty*4 + p;
    if (r < N){
      float4 o;
      o.x = fmaxf(acc[p][0] + bv.x, 0.f);
      o.y = fmaxf(acc[p][1] + bv.y, 0.f);
      o.z = fmaxf(acc[p][2] + bv.z, 0.f);
      o.w = fmaxf(acc[p][3] + bv.w, 0.f);
      *(float4*)(h1 + (size_t)r*64 + tx*4) = o;
    }
  }
}

// ---------------- small GEMM: Y = epi(X(n,64) @ W(64,CO) + bias) ----------
// EPI: 0=none 1=relu 3=softplus. X stride 64, Y stride CO.
template<int CO, int EPI>
__global__ __launch_bounds__(256) void k_sg(
    const float* __restrict__ X, const float* __restrict__ W, const float* __restrict__ bias,
    float* __restrict__ Y, int n){
  constexpr int CPT = CO/16;
  __shared__ float XsT[64*68];
  __shared__ float Ws[64*CO];
  int tid = threadIdx.x;
  int row0 = blockIdx.x*64;
  {
    int xr = tid >> 2, q = (tid & 3)*16;
    int row = row0 + xr;
    #pragma unroll
    for (int i = 0; i < 4; ++i){
      float4 v = make_float4(0,0,0,0);
      if (row < n) v = *(const float4*)(X + (size_t)row*64 + q + i*4);
      XsT[(q+i*4+0)*68 + xr] = v.x;
      XsT[(q+i*4+1)*68 + xr] = v.y;
      XsT[(q+i*4+2)*68 + xr] = v.z;
      XsT[(q+i*4+3)*68 + xr] = v.w;
    }
  }
  for (int i = tid*4; i < 64*CO; i += 1024)
    *(float4*)(Ws + i) = *(const float4*)(W + i);
  __syncthreads();
  int tx = tid & 15, ty = tid >> 4;
  int colbase = tx*CPT;
  float acc[4][CPT];
  #pragma unroll
  for (int p = 0; p < 4; ++p)
    #pragma unroll
    for (int c = 0; c < CPT; ++c) acc[p][c] = 0.f;
  #pragma unroll 8
  for (int k = 0; k < 64; ++k){
    float4 xv = *(const float4*)(XsT + k*68 + ty*4);
    float xp[4] = {xv.x, xv.y, xv.z, xv.w};
    float wv[CPT];
    if constexpr (CPT == 8){
      float4 t0 = *(const float4*)(Ws + k*CO + colbase);
      float4 t1 = *(const float4*)(Ws + k*CO + colbase + 4);
      wv[0]=t0.x; wv[1]=t0.y; wv[2]=t0.z; wv[3]=t0.w;
      wv[4]=t1.x; wv[5]=t1.y; wv[6]=t1.z; wv[7]=t1.w;
    } else if constexpr (CPT == 4){
      float4 t0 = *(const float4*)(Ws + k*CO + colbase);
      wv[0]=t0.x; wv[1]=t0.y; wv[2]=t0.z; wv[3]=t0.w;
    } else {
      float2 t0 = *(const float2*)(Ws + k*CO + colbase);
      wv[0]=t0.x; wv[1]=t0.y;
    }
    #pragma unroll
    for (int p = 0; p < 4; ++p)
      #pragma unroll
      for (int c = 0; c < CPT; ++c) acc[p][c] = fmaf(xp[p], wv[c], acc[p][c]);
  }
  float bv[CPT];
  #pragma unroll
  for (int c = 0; c < CPT; ++c) bv[c] = bias ? bias[colbase + c] : 0.f;
  #pragma unroll
  for (int p = 0; p < 4; ++p){
    int row = row0 + ty*4 + p;
    if (row < n){
      float o[CPT];
      #pragma unroll
      for (int c = 0; c < CPT; ++c){
        float v = acc[p][c] + bv[c];
        if constexpr (EPI == 1) v = fmaxf(v, 0.f);
        if constexpr (EPI == 3) v = softplusf_dev(v);
        o[c] = v;
      }
      if constexpr (CPT == 8){
        *(float4*)(Y + (size_t)row*CO + colbase)     = make_float4(o[0],o[1],o[2],o[3]);
        *(float4*)(Y + (size_t)row*CO + colbase + 4) = make_float4(o[4],o[5],o[6],o[7]);
      } else if constexpr (CPT == 4){
        *(float4*)(Y + (size_t)row*CO + colbase) = make_float4(o[0],o[1],o[2],o[3]);
      } else {
        *(float2*)(Y + (size_t)row*CO + colbase) = make_float2(o[0],o[1]);
      }
    }
  }
}

// ---------------- fused update MLP + residual LN ----------------
// hout = LN(hin + (relu(neigh@W1+b1))@W2 + b2)
__global__ __launch_bounds__(256) void k_upd(
    const float* __restrict__ neigh, const float* __restrict__ W1, const float* __restrict__ b1,
    const float* __restrict__ W2, const float* __restrict__ b2,
    const float* __restrict__ lng, const float* __restrict__ lnb,
    const float* __restrict__ hin, float* __restrict__ hout, int n){
  __shared__ float XsT[64*68];
  __shared__ float W1s[64*64];
  __shared__ float W2s[64*64];
  int tid = threadIdx.x;
  int row0 = blockIdx.x*64;
  {
    int xr = tid >> 2, q = (tid & 3)*16;
    int row = row0 + xr;
    #pragma unroll
    for (int i = 0; i < 4; ++i){
      float4 v = make_float4(0,0,0,0);
      if (row < n) v = *(const float4*)(neigh + (size_t)row*64 + q + i*4);
      XsT[(q+i*4+0)*68 + xr] = v.x;
      XsT[(q+i*4+1)*68 + xr] = v.y;
      XsT[(q+i*4+2)*68 + xr] = v.z;
      XsT[(q+i*4+3)*68 + xr] = v.w;
    }
  }
  for (int i = tid*4; i < 4096; i += 1024){
    *(float4*)(W1s + i) = *(const float4*)(W1 + i);
    *(float4*)(W2s + i) = *(const float4*)(W2 + i);
  }
  __syncthreads();
  int tx = tid & 15, ty = tid >> 4;
  float acc[4][4];
  #pragma unroll
  for (int p = 0; p < 4; ++p){ acc[p][0]=0; acc[p][1]=0; acc[p][2]=0; acc[p][3]=0; }
  #pragma unroll 8
  for (int k = 0; k < 64; ++k){
    float4 xv = *(const float4*)(XsT + k*68 + ty*4);
    float4 wv = *(const float4*)(W1s + k*64 + tx*4);
    float xp[4] = {xv.x, xv.y, xv.z, xv.w};
    #pragma unroll
    for (int p = 0; p < 4; ++p){
      acc[p][0] = fmaf(xp[p], wv.x, acc[p][0]);
      acc[p][1] = fmaf(xp[p], wv.y, acc[p][1]);
      acc[p][2] = fmaf(xp[p], wv.z, acc[p][2]);
      acc[p][3] = fmaf(xp[p], wv.w, acc[p][3]);
    }
  }
  float4 b1v = *(const float4*)(b1 + tx*4);
  float hd[4][4];
  #pragma unroll
  for (int p = 0; p < 4; ++p){
    hd[p][0] = fmaxf(acc[p][0] + b1v.x, 0.f);
    hd[p][1] = fmaxf(acc[p][1] + b1v.y, 0.f);
    hd[p][2] = fmaxf(acc[p][2] + b1v.z, 0.f);
    hd[p][3] = fmaxf(acc[p][3] + b1v.w, 0.f);
  }
  __syncthreads();   // all XsT reads done
  #pragma unroll
  for (int p = 0; p < 4; ++p)
    #pragma unroll
    for (int c = 0; c < 4; ++c)
      XsT[(tx*4 + c)*68 + (ty*4 + p)] = hd[p][c];   // hidden, transposed
  __syncthreads();
  #pragma unroll
  for (int p = 0; p < 4; ++p){ acc[p][0]=0; acc[p][1]=0; acc[p][2]=0; acc[p][3]=0; }
  #pragma unroll 8
  for (int k = 0; k < 64; ++k){
    float4 xv = *(const float4*)(XsT + k*68 + ty*4);
    float4 wv = *(const float4*)(W2s + k*64 + tx*4);
    float xp[4] = {xv.x, xv.y, xv.z, xv.w};
    #pragma unroll
    for (int p = 0; p < 4; ++p){
      acc[p][0] = fmaf(xp[p], wv.x, acc[p][0]);
      acc[p][1] = fmaf(xp[p], wv.y, acc[p][1]);
      acc[p][2] = fmaf(xp[p], wv.z, acc[p][2]);
      acc[p][3] = fmaf(xp[p], wv.w, acc[p][3]);
    }
  }
  float4 b2v = *(const float4*)(b2 + tx*4);
  float lg[4] = {lng[tx*4], lng[tx*4+1], lng[tx*4+2], lng[tx*4+3]};
  float lb[4] = {lnb[tx*4], lnb[tx*4+1], lnb[tx*4+2], lnb[tx*4+3]};
  float hn[4][4];
  #pragma unroll
  for (int p = 0; p < 4; ++p){
    int row = row0 + ty*4 + p;
    float4 hv = (row < n) ? *(const float4*)(hin + (size_t)row*64 + tx*4) : make_float4(0,0,0,0);
    hn[p][0] = hv.x + acc[p][0] + b2v.x;
    hn[p][1] = hv.y + acc[p][1] + b2v.y;
    hn[p][2] = hv.z + acc[p][2] + b2v.z;
    hn[p][3] = hv.w + acc[p][3] + b2v.w;
  }
  float rs[4], vs[4];
  #pragma unroll
  for (int p = 0; p < 4; ++p) rs[p] = hn[p][0]+hn[p][1]+hn[p][2]+hn[p][3];
  #pragma unroll
  for (int m = 8; m >= 1; m >>= 1)
    #pragma unroll
    for (int p = 0; p < 4; ++p) rs[p] += __shfl_xor(rs[p], m, 64);
  float mean[4], inv[4];
  #pragma unroll
  for (int p = 0; p < 4; ++p) mean[p] = rs[p] * 0.015625f;
  #pragma unroll
  for (int p = 0; p < 4; ++p){
    float d0 = hn[p][0]-mean[p], d1 = hn[p][1]-mean[p];
    float d2 = hn[p][2]-mean[p], d3 = hn[p][3]-mean[p];
    vs[p] = d0*d0 + d1*d1 + d2*d2 + d3*d3;
  }
  #pragma unroll
  for (int m = 8; m >= 1; m >>= 1)
    #pragma unroll
    for (int p = 0; p < 4; ++p) vs[p] += __shfl_xor(vs[p], m, 64);
  #pragma unroll
  for (int p = 0; p < 4; ++p) inv[p] = 1.f / sqrtf(vs[p]*0.015625f + 1e-5f);
  #pragma unroll
  for (int p = 0; p < 4; ++p){
    int row = row0 + ty*4 + p;
    if (row < n){
      float4 o;
      o.x = fmaf(lg[0], (hn[p][0]-mean[p])*inv[p], lb[0]);
      o.y = fmaf(lg[1], (hn[p][1]-mean[p])*inv[p], lb[1]);
      o.z = fmaf(lg[2], (hn[p][2]-mean[p])*inv[p], lb[2]);
      o.w = fmaf(lg[3], (hn[p][3]-mean[p])*inv[p], lb[3]);
      *(float4*)(hout + (size_t)row*64 + tx*4) = o;
    }
  }
}

// ---------------- edge gate: one wave per edge -> sw[e] = (src_bits, w) -----
__global__ __launch_bounds__(256) void k_gate(
    const float4* __restrict__ csr4, const float* __restrict__ ab,
    const float* __restrict__ rho,
    const float* __restrict__ gw1, const float* __restrict__ gw2,
    const float* __restrict__ gb2, float2* __restrict__ sw, int E){
  int e = (blockIdx.x*256 + threadIdx.x) >> 6;
  int j = threadIdx.x & 63;
  if (e >= E) return;
  float4 ce = csr4[e];
  int s = __float_as_int(ce.x);
  int d = __float_as_int(ce.w);
  float a = ab[(size_t)s*128 + j];
  float b = ab[(size_t)d*128 + 64 + j];        // includes gb1
  float t = fmaxf(fmaf(ce.y, gw1[128*64 + j], a + b), 0.f) * gw2[j];
  t += __shfl_xor(t, 32, 64);
  t += __shfl_xor(t, 16, 64);
  t += __shfl_xor(t,  8, 64);
  t += __shfl_xor(t,  4, 64);
  t += __shfl_xor(t,  2, 64);
  t += __shfl_xor(t,  1, 64);
  if (j == 0){
    float w = sigmoidf_fast(t + gb2[0]) * ce.z * rho[d];   // ce.z = base_w*rho[src]
    sw[e] = make_float2(ce.x, w);
  }
}

// ---------------- aggregation: pure gather-FMA, 4-edge unroll ----------------
__global__ __launch_bounds__(256) void k_agg(
    const float* __restrict__ h, const float2* __restrict__ sw,
    const int* __restrict__ offs, float* __restrict__ neigh, int N){
  int v = (blockIdx.x*256 + threadIdx.x) >> 6;
  int j = threadIdx.x & 63;
  if (v >= N) return;
  int beg = offs[v], end = offs[v+1];
  float acc = 0.f, deg = 0.f;
  int i = beg;
  for (; i + 4 <= end; i += 4){
    float2 e0 = sw[i], e1 = sw[i+1], e2 = sw[i+2], e3 = sw[i+3];
    float h0 = h[(size_t)__float_as_int(e0.x)*64 + j];
    float h1 = h[(size_t)__float_as_int(e1.x)*64 + j];
    float h2 = h[(size_t)__float_as_int(e2.x)*64 + j];
    float h3 = h[(size_t)__float_as_int(e3.x)*64 + j];
    acc = fmaf(e0.y, h0, acc);
    acc = fmaf(e1.y, h1, acc);
    acc = fmaf(e2.y, h2, acc);
    acc = fmaf(e3.y, h3, acc);
    deg += (e0.y + e1.y) + (e2.y + e3.y);
  }
  for (; i < end; ++i){
    float2 e0 = sw[i];
    acc = fmaf(e0.y, h[(size_t)__float_as_int(e0.x)*64 + j], acc);
    deg += e0.y;
  }
  neigh[(size_t)v*64 + j] = acc * __builtin_amdgcn_rcpf(deg + 1e-8f);
}

// ---------------- final: mu = exp(clip(loglib + log(U@W^T) + alpha + bcorr))
__global__ __launch_bounds__(256) void k_final(
    const float* __restrict__ U, const float* __restrict__ WT,
    const float* __restrict__ alpha, const float* __restrict__ bcorr,
    const float* __restrict__ loglib, const int* __restrict__ sid,
    float* __restrict__ out, int N, int C, int S, int npb){
  int c = blockIdx.x*256 + threadIdx.x;
  bool act = (c < C);
  int cc = act ? c : (C-1);
  float wreg[32];
  #pragma unroll
  for (int k = 0; k < 32; ++k) wreg[k] = WT[k*C + cc];
  float al = alpha[cc];
  float bc8[8];
  #pragma unroll
  for (int s = 0; s < 8; ++s) bc8[s] = bcorr[min(s, S-1)*C + cc];
  int n0 = blockIdx.y * npb;
  int n1 = min(n0 + npb, N);
  for (int n = n0; n + 4 <= n1; n += 4){
    int sd0 = sid[n], sd1 = sid[n+1], sd2 = sid[n+2], sd3 = sid[n+3];
    float l0 = loglib[n], l1 = loglib[n+1], l2 = loglib[n+2], l3 = loglib[n+3];
    const float* u0 = U + (size_t)n*32;
    const float* u1 = u0 + 32;
    const float* u2 = u0 + 64;
    const float* u3 = u0 + 96;
    float d0 = 0.f, d1 = 0.f, d2 = 0.f, d3 = 0.f;
    #pragma unroll
    for (int k = 0; k < 32; ++k){
      d0 = fmaf(u0[k], wreg[k], d0);
      d1 = fmaf(u1[k], wreg[k], d1);
      d2 = fmaf(u2[k], wreg[k], d2);
      d3 = fmaf(u3[k], wreg[k], d3);
    }
    float b0 = bc8[0], b1 = bc8[0], b2 = bc8[0], b3 = bc8[0];
    #pragma unroll
    for (int s = 1; s < 8; ++s){
      b0 = (sd0 == s) ? bc8[s] : b0;
      b1 = (sd1 == s) ? bc8[s] : b1;
      b2 = (sd2 == s) ? bc8[s] : b2;
      b3 = (sd3 == s) ? bc8[s] : b3;
    }
    float m0 = l0 + __logf(fmaxf(d0, 1e-8f)) + al + b0;
    float m1 = l1 + __logf(fmaxf(d1, 1e-8f)) + al + b1;
    float m2 = l2 + __logf(fmaxf(d2, 1e-8f)) + al + b2;
    float m3 = l3 + __logf(fmaxf(d3, 1e-8f)) + al + b3;
    m0 = fminf(fmaxf(m0, -20.f), 20.f);
    m1 = fminf(fmaxf(m1, -20.f), 20.f);
    m2 = fminf(fmaxf(m2, -20.f), 20.f);
    m3 = fminf(fmaxf(m3, -20.f), 20.f);
    if (act){
      __builtin_nontemporal_store(__expf(m0), &out[(size_t)n*C + c]);
      __builtin_nontemporal_store(__expf(m1), &out[(size_t)(n+1)*C + c]);
      __builtin_nontemporal_store(__expf(m2), &out[(size_t)(n+2)*C + c]);
      __builtin_nontemporal_store(__expf(m3), &out[(size_t)(n+3)*C + c]);
    }
  }
}

// ---------------------------------------------------------------------------
extern "C" void kernel_launch(void* const* d_in, const int* in_sizes, int n_in,
                              void* d_out, int out_size, void* d_ws, size_t ws_size,
                              hipStream_t stream){
  const float* x_common = (const float*)d_in[0];
  const int*   src      = (const int*)  d_in[1];
  const int*   dst      = (const int*)  d_in[2];
  const float* base_w   = (const float*)d_in[3];
  const float* dist     = (const float*)d_in[4];
  const float* lib      = (const float*)d_in[5];
  const int*   sid      = (const int*)  d_in[6];
  const float* enc_w1   = (const float*)d_in[7];
  const float* enc_b1   = (const float*)d_in[8];
  const float* enc_w2   = (const float*)d_in[9];
  const float* enc_b2   = (const float*)d_in[10];
  const float* upd_w1   = (const float*)d_in[11];
  const float* upd_b1   = (const float*)d_in[12];
  const float* upd_w2   = (const float*)d_in[13];
  const float* upd_b2   = (const float*)d_in[14];
  const float* ln_g     = (const float*)d_in[15];
  const float* ln_b     = (const float*)d_in[16];
  const float* gate_w1  = (const float*)d_in[17];
  const float* gate_b1  = (const float*)d_in[18];
  const float* gate_w2  = (const float*)d_in[19];
  const float* gate_b2  = (const float*)d_in[20];
  const float* rho_raw  = (const float*)d_in[21];
  const float* toU_w    = (const float*)d_in[22];
  const float* toU_b    = (const float*)d_in[23];
  const float* W_raw    = (const float*)d_in[24];
  const float* alpha    = (const float*)d_in[25];
  const float* P        = (const float*)d_in[26];
  const float* Q        = (const float*)d_in[27];

  const int N = in_sizes[5];            // 50000
  const int E = in_sizes[1];            // 800000
  const int C = in_sizes[25];           // 1000
  const int K = in_sizes[23];           // 32
  const int R = in_sizes[27] / C;       // 16
  const int S = in_sizes[26] / R;       // 8
  const int L = in_sizes[15] / 64;      // 2

  float* w = (float*)d_ws;
  size_t o = 0;
  auto alloc = [&](size_t nf)->float*{ float* p = w + o; o += (nf + 63) & ~((size_t)63); return p; };
  float*  hA    = alloc((size_t)N*64);
  float*  hB    = alloc((size_t)N*64);
  float*  ab    = alloc((size_t)N*128);
  float*  neigh = alloc((size_t)N*64);   // also enc1 h1 scratch
  float*  Ubuf  = alloc((size_t)N*32);
  float*  rho   = alloc((size_t)N);
  float*  loglib= alloc((size_t)N);
  float*  WT    = alloc((size_t)K*C);
  float*  bcorr = alloc((size_t)S*C);
  float*  Wg    = alloc((size_t)64*128);
  float*  biasg = alloc(128);
  float4* csr4  = (float4*)alloc((size_t)E*4);
  float2* sw    = (float2*)alloc((size_t)E*2);
  int*    cnt   = (int*)alloc((size_t)N);
  int*    offs  = (int*)alloc((size_t)N + 64);
  int*    fillc = (int*)alloc((size_t)N);
  int*    blksum= (int*)alloc(256);

  hipMemsetAsync(cnt,   0, sizeof(int)*(size_t)N, stream);
  hipMemsetAsync(fillc, 0, sizeof(int)*(size_t)N, stream);

  // prep
  k_prep_node<<<(N+255)/256,256,0,stream>>>(rho_raw, lib, rho, loglib, N);
  k_prep_W<<<(K*C+255)/256,256,0,stream>>>(W_raw, WT, C, K);
  k_prep_bcorr<<<1,256,0,stream>>>(P, Q, bcorr, S, R, C);
  k_repack<<<32,256,0,stream>>>(gate_w1, gate_b1, Wg, biasg);

  // CSR by dst
  k_hist<<<(E+255)/256,256,0,stream>>>(dst, cnt, E);
  int nblk = (N+1023)/1024;
  k_scan1<<<nblk,1024,0,stream>>>(cnt, offs, blksum, N);
  k_scan2<<<1,64,0,stream>>>(blksum, nblk);
  k_scan3<<<(N+256)/256,256,0,stream>>>(offs, blksum, N, E);
  k_fill<<<(E+255)/256,256,0,stream>>>(src, dst, base_w, dist, rho, offs, fillc, csr4, E);

  // encoder
  int g64 = (N+63)/64;
  k_enc1<<<g64,256,0,stream>>>(x_common, enc_w1, enc_b1, neigh, N, C);
  k_sg<64,1><<<g64,256,0,stream>>>(neigh, enc_w2, enc_b2, hA, N);
  k_sg<128,0><<<g64,256,0,stream>>>(hA, Wg, biasg, ab, N);

  float* cur = hA; float* nxt = hB;
  for (int l = 0; l < L; ++l){
    k_gate<<<(E+3)/4,256,0,stream>>>(csr4, ab, rho, gate_w1, gate_w2, gate_b2, sw, E);
    k_agg<<<(N+3)/4,256,0,stream>>>(cur, sw, offs, neigh, N);
    k_upd<<<g64,256,0,stream>>>(neigh, upd_w1 + (size_t)l*64*64, upd_b1 + l*64,
                                upd_w2 + (size_t)l*64*64, upd_b2 + l*64,
                                ln_g + l*64, ln_b + l*64, cur, nxt, N);
    if (l + 1 < L)
      k_sg<128,0><<<g64,256,0,stream>>>(nxt, Wg, biasg, ab, N);
    float* t = cur; cur = nxt; nxt = t;
  }

  // U = softplus(h @ toU_w + toU_b)
  k_sg<32,3><<<g64,256,0,stream>>>(cur, toU_w, toU_b, Ubuf, N);

  // mu
  dim3 fg((C+255)/256, (N+15)/16);
  k_final<<<fg,256,0,stream>>>(Ubuf, WT, alpha, bcorr, loglib, sid, (float*)d_out, N, C, S, 16);
}